// Round 11
// baseline (803.760 us; speedup 1.0000x reference)
//
#include <hip/hip_runtime.h>
#include <math.h>

typedef __attribute__((ext_vector_type(8))) short s16x8;
typedef __attribute__((ext_vector_type(4))) short s16x4;
typedef __attribute__((ext_vector_type(4))) float f32x4;

typedef unsigned int u32;
typedef __attribute__((address_space(3))) u32* lds_u32p;
typedef const __attribute__((address_space(1))) u32* glb_u32p;

namespace {

constexpr int B  = 8;
constexpr int C  = 192;
constexpr int H  = 96;
constexpr int W  = 96;
constexpr int FK = 9;
constexpr int HP = 98;    // padded
constexpr int L  = 1024;  // 32x32 patch grid per phase
constexpr int WCHUNK = FK * 12 * 6;          // 648 packed 1KB chunks per tensor
constexpr int WELEM  = WCHUNK * 512;         // 331776 bf16 elements
constexpr size_t XPAD_ELEMS = (size_t)B * HP * HP * 192;

__device__ inline unsigned short f2b(float f) {
    unsigned int x = __float_as_uint(f);
    x += 0x7fffu + ((x >> 16) & 1u);
    return (unsigned short)(x >> 16);
}

// ---------------------------------------------------------------------------
// zero ONLY the pad borders of both xpad tensors (replaces 59MB memset).
// ---------------------------------------------------------------------------
__global__ __launch_bounds__(256) void border_zero(unsigned short* __restrict__ xpad) {
    const int c   = blockIdx.x * 256 + threadIdx.x;
    const int c16 = c % 24;
    const int p_  = c / 24;
    const int pos = p_ % 388;
    const int bt  = p_ / 388;      // 0..15 spans xpad1 then xpad2
    int yy, xx;
    if (pos < 98)       { yy = 0;          xx = pos; }
    else if (pos < 196) { yy = 97;         xx = pos - 98; }
    else if (pos < 292) { yy = pos - 195;  xx = 0; }
    else                { yy = pos - 291;  xx = 97; }
    const size_t off = (((size_t)bt * HP + yy) * HP + xx) * 192 + c16 * 8;
    *(s16x8*)(xpad + off) = (s16x8){0, 0, 0, 0, 0, 0, 0, 0};
}

// ---------------------------------------------------------------------------
// x[b][c][96][96] f32 -> xpadT[b][98][98][192] bf16 (both tensors, z=16)
// ---------------------------------------------------------------------------
__global__ __launch_bounds__(256) void prep_x(const float* __restrict__ x1,
                                              const float* __restrict__ x2,
                                              unsigned short* __restrict__ xpadT) {
    __shared__ float xs[192][33];
    const int tid = threadIdx.x;
    const int x0  = blockIdx.x * 32;
    const int y   = blockIdx.y;
    const int zz  = blockIdx.z;
    const int b   = zz & 7, t = zz >> 3;
    const float* x = t ? x2 : x1;
    unsigned short* dst = xpadT + (size_t)t * XPAD_ELEMS;
    for (int e = tid; e < 192 * 32; e += 256) {
        const int ci = e >> 5, xx = e & 31;
        xs[ci][xx] = x[(((size_t)b * C + ci) * H + y) * W + x0 + xx];
    }
    __syncthreads();
    for (int e = tid; e < 32 * 192; e += 256) {
        const int pos = e / 192, ci = e - pos * 192;
        dst[(((size_t)(b * HP + y + 1)) * HP + x0 + pos + 1) * 192 + ci] = f2b(xs[ci][pos]);
    }
}

// ---------------------------------------------------------------------------
// pack weights into fragment-linear layout:
//   dst[(((p*12 + cot)*6 + cc))*512 + lane*8 + t]  = w[co][ci][p]
// ---------------------------------------------------------------------------
__global__ __launch_bounds__(256) void prep_w(const float* __restrict__ kw,
                                              const float* __restrict__ qw,
                                              unsigned short* __restrict__ kwA,
                                              unsigned short* __restrict__ qwA) {
    int idx = blockIdx.x * 256 + threadIdx.x;
    const float* src = kw;
    unsigned short* dst = kwA;
    if (idx >= WELEM) { idx -= WELEM; src = qw; dst = qwA; }
    const int chunk = idx >> 9, within = idx & 511;
    const int lane = within >> 3, t = within & 7;
    const int kg = lane >> 4, r15 = lane & 15;
    const int cc = chunk % 6, c2 = chunk / 6;
    const int cot = c2 % 12, p = c2 / 12;
    const int co = cot * 16 + r15;
    const int ci = cc * 32 + kg * 8 + t;
    dst[idx] = f2b(src[((size_t)co * C + ci) * FK + p]);
}

// ---------------------------------------------------------------------------
// MFMA implicit-GEMM conv3x3: 4 output rows per block, rolling LDS slots.
// Block: 256 thr = 4 waves; wave wc = co strip wc*48, 48 s, 2 y per ystep.
// Slots: 4 x 19.2KB row windows (76.8KB, 2 blocks/CU). ystep0 computes
// y0,y0+1 from slots 0-3 (rows y0..y0+3); restage rows y0+4,y0+5 into slots
// 0,1 issued BEFORE ystep0 epilogue (latency hides under stores); ystep1
// computes y0+2,y0+3 from slots 2,3,0,1. Batched 9-af per (dy,cc) (R8).
// XCD-chunked y: y0 = ((xb%8)*3 + xb/8)*4 -> contiguous 12-row band per XCD.
// NOTE: (256,2) — (256,4)/(256,3)-with-big-unroll spilled (R7/R9).
// DUAL: grid.z=16 encodes (tensor, b).
// ---------------------------------------------------------------------------
template <bool OUTF32, bool PERB, bool DUAL>
__global__ __launch_bounds__(256, 2)
void conv_mfma(const unsigned short* __restrict__ xpadA,
               const unsigned short* __restrict__ xpadB,
               const unsigned short* __restrict__ wA,
               const unsigned short* __restrict__ wB,
               void* __restrict__ youtA,
               void* __restrict__ youtB) {
    __shared__ __align__(16) char smem[4 * 19200];   // 76800 B
    const int tid  = threadIdx.x;
    const int xb   = blockIdx.x;                     // 0..23
    const int y0   = ((xb & 7) * 3 + (xb >> 3)) * 4; // XCD-chunked, bijective
    const int sx   = blockIdx.y;        // s half (48 outputs)
    const int zz   = blockIdx.z;
    const int b    = DUAL ? (zz & 7) : zz;
    const int t    = DUAL ? (zz >> 3) : 0;
    const unsigned short* xpadT = (DUAL && t) ? xpadB : xpadA;
    const unsigned short* wbase = (DUAL && t) ? wB : wA;
    void* yout = (DUAL && t) ? youtB : youtA;
    const int lane = tid & 63, wc = tid >> 6;
    const int ln15 = lane & 15, kg = lane >> 4;

    const unsigned short* wp = PERB ? (wbase + (size_t)b * WELEM) : wbase;

    // per-row staging: 50 pos x 24 chunks(16B) = 1200; 4 full rounds + 176 tail
    int gfull[4];
#pragma unroll
    for (int it = 0; it < 4; ++it) {
        const int m = it * 256 + tid;
        const int q = m / 24, c16 = m - q * 24;
        gfull[it] = (sx * 48 + q) * 384 + ((c16 * 16) ^ ((q & 7) << 4));
    }
    int gtail = 0;
    if (tid < 176) {
        const int m = 1024 + tid;
        const int q = m / 24, c16 = m - q * 24;
        gtail = (sx * 48 + q) * 384 + ((c16 * 16) ^ ((q & 7) << 4));
    }

    auto stageRow = [&](int slot, int prow) {
        const char* rb = (const char*)(xpadT + ((size_t)(b * HP + prow)) * HP * 192);
        char* lb = smem + slot * 19200;
#pragma unroll
        for (int it = 0; it < 4; ++it)
            __builtin_amdgcn_global_load_lds(
                (glb_u32p)(const void*)(rb + gfull[it]),
                (lds_u32p)(void*)(lb + it * 4096 + wc * 1024), 16, 0, 0);
        if (tid < 176)
            __builtin_amdgcn_global_load_lds(
                (glb_u32p)(const void*)(rb + gtail),
                (lds_u32p)(void*)(lb + 16384 + wc * 1024), 16, 0, 0);
    };

    // initial: rows y0..y0+3 -> slots 0..3
    stageRow(0, y0);
    stageRow(1, y0 + 1);
    stageRow(2, y0 + 2);
    stageRow(3, y0 + 3);
    asm volatile("s_waitcnt vmcnt(0)" ::: "memory");
    __syncthreads();

#pragma unroll
    for (int s = 0; s < 2; ++s) {
        f32x4 acc[2][3][3];
#pragma unroll
        for (int yy = 0; yy < 2; ++yy)
#pragma unroll
            for (int i = 0; i < 3; ++i)
#pragma unroll
                for (int j = 0; j < 3; ++j)
                    acc[yy][i][j] = (f32x4){0.f, 0.f, 0.f, 0.f};

#pragma unroll
        for (int dy = 0; dy < 3; ++dy) {
#pragma unroll
            for (int cc = 0; cc < 6; ++cc) {
                s16x8 af[3][3];
#pragma unroll
                for (int dx = 0; dx < 3; ++dx)
#pragma unroll
                    for (int i = 0; i < 3; ++i) {
                        const int chunkid = ((3 * dy + dx) * 12 + wc * 3 + i) * 6 + cc;
                        af[dx][i] = *(const s16x8*)(wp + (size_t)chunkid * 512 + lane * 8);
                    }
#pragma unroll
                for (int yy = 0; yy < 2; ++yy) {
                    const int slot = (2 * s + dy + yy) & 3;   // compile-time
                    s16x8 bv[3][3];
#pragma unroll
                    for (int j = 0; j < 3; ++j)
#pragma unroll
                        for (int dx = 0; dx < 3; ++dx) {
                            const int q = j * 16 + ln15 + dx;
                            bv[j][dx] = *(const s16x8*)(smem + slot * 19200 + q * 384 +
                                            ((cc * 64 + kg * 16) ^ ((q & 7) << 4)));
                        }
#pragma unroll
                    for (int i = 0; i < 3; ++i)
#pragma unroll
                        for (int j = 0; j < 3; ++j)
#pragma unroll
                            for (int dx = 0; dx < 3; ++dx)
                                acc[yy][i][j] = __builtin_amdgcn_mfma_f32_16x16x32_bf16(
                                    af[dx][i], bv[j][dx], acc[yy][i][j], 0, 0, 0);
                }
            }
        }

        if (s == 0) {
            __syncthreads();                 // all waves done reading slots 0,1
            stageRow(0, y0 + 4);             // restage issues; latency hides
            stageRow(1, y0 + 5);             // under the epilogue stores below
        }

        // ---- epilogue for y = y0+2s, y0+2s+1 ----
#pragma unroll
        for (int yy = 0; yy < 2; ++yy) {
            const int y = y0 + 2 * s + yy;
            if (!OUTF32) {
                unsigned short* yb = (unsigned short*)yout;
                const int ph = y % 3, lh = y / 3;
                int poff[3];
#pragma unroll
                for (int j = 0; j < 3; ++j) {
                    const int ss = sx * 48 + j * 16 + ln15;
                    const int pw = ss % 3, lw = ss / 3;
                    poff[j] = ((b * FK + ph * 3 + pw) * C) * L + lh * 32 + lw;
                }
#pragma unroll
                for (int i = 0; i < 3; ++i)
#pragma unroll
                    for (int rr = 0; rr < 4; ++rr) {
                        const int co = wc * 48 + i * 16 + kg * 4 + rr;
#pragma unroll
                        for (int j = 0; j < 3; ++j)
                            yb[(size_t)poff[j] + co * L] = f2b(acc[yy][i][j][rr]);
                    }
            } else {
                float* yf = (float*)yout;
#pragma unroll
                for (int i = 0; i < 3; ++i)
#pragma unroll
                    for (int rr = 0; rr < 4; ++rr) {
                        const int co = wc * 48 + i * 16 + kg * 4 + rr;
                        const size_t base = (((size_t)b * C + co) * H + y) * W;
#pragma unroll
                        for (int j = 0; j < 3; ++j)
                            yf[base + sx * 48 + j * 16 + ln15] = acc[yy][i][j][rr];
                    }
            }
        }

        if (s == 0) {
            asm volatile("s_waitcnt vmcnt(0)" ::: "memory");
            __syncthreads();                 // slots 0,1 now rows y0+4,y0+5
        }
    }
}

// ---------------------------------------------------------------------------
// attn MFMA: per (b,phase) GEMM D[c][o] = sum_k Kc[c][k]*Qc[o][k], K=1024.
// Block = 96c x 96o quarter, 4 waves 48x48. BK=64 double-buffered staging.
// Epilogue: attnT[b][p][o][c] f32 + fused f64 sum/ssq partials.
// ---------------------------------------------------------------------------
__global__ __launch_bounds__(256, 3)
void attn_mfma(const unsigned short* __restrict__ kcS,
               const unsigned short* __restrict__ qcS,
               float* __restrict__ attnT,
               double* __restrict__ part) {
    __shared__ __align__(16) char smem[2][24576];   // [buf][A 12KB | B 12KB]
    const int tid  = threadIdx.x;
    const int lane = tid & 63, wid = tid >> 6;
    const int wq   = wid & 1, wp = wid >> 1;
    const int ln15 = lane & 15, kg = lane >> 4;
    const int of   = blockIdx.x & 1, cf = blockIdx.x >> 1;
    const int p    = blockIdx.y, b = blockIdx.z;

    const char* Abase = (const char*)(kcS + ((size_t)(b * FK + p) * C + cf * 96) * L);
    const char* Bbase = (const char*)(qcS + ((size_t)(b * FK + p) * C + of * 96) * L);

    int gofs[3];
#pragma unroll
    for (int it = 0; it < 3; ++it) {
        const int chunk = it * 256 + tid;
        const int row = chunk >> 3, c16 = chunk & 7;
        gofs[it] = row * 2048 + ((c16 * 16) ^ ((row & 7) << 4));
    }

    auto stage = [&](int bufi, int t) {
        const char* Ab = Abase + t * 128;
        const char* Bb = Bbase + t * 128;
        char* lb = (char*)smem[bufi];
#pragma unroll
        for (int it = 0; it < 3; ++it)
            __builtin_amdgcn_global_load_lds(
                (glb_u32p)(const void*)(Ab + gofs[it]),
                (lds_u32p)(void*)(lb + it * 4096 + wid * 1024), 16, 0, 0);
#pragma unroll
        for (int it = 0; it < 3; ++it)
            __builtin_amdgcn_global_load_lds(
                (glb_u32p)(const void*)(Bb + gofs[it]),
                (lds_u32p)(void*)(lb + 12288 + it * 4096 + wid * 1024), 16, 0, 0);
    };

    f32x4 acc[3][3];
#pragma unroll
    for (int i = 0; i < 3; ++i)
#pragma unroll
        for (int j = 0; j < 3; ++j)
            acc[i][j] = (f32x4){0.f, 0.f, 0.f, 0.f};

    stage(0, 0);
    asm volatile("s_waitcnt vmcnt(0)" ::: "memory");
    __syncthreads();

    for (int t = 0; t < 16; ++t) {
        if (t < 15) stage((t + 1) & 1, t + 1);
        const char* lb = (const char*)smem[t & 1];
#pragma unroll
        for (int ks = 0; ks < 2; ++ks) {
            s16x8 af[3], bf[3];
#pragma unroll
            for (int i = 0; i < 3; ++i) {
                const int row = wp * 48 + i * 16 + ln15;
                af[i] = *(const s16x8*)(lb + row * 128 +
                                        ((ks * 64 + kg * 16) ^ ((row & 7) << 4)));
            }
#pragma unroll
            for (int j = 0; j < 3; ++j) {
                const int row = wq * 48 + j * 16 + ln15;
                bf[j] = *(const s16x8*)(lb + 12288 + row * 128 +
                                        ((ks * 64 + kg * 16) ^ ((row & 7) << 4)));
            }
#pragma unroll
            for (int i = 0; i < 3; ++i)
#pragma unroll
                for (int j = 0; j < 3; ++j)
                    acc[i][j] = __builtin_amdgcn_mfma_f32_16x16x32_bf16(
                        af[i], bf[j], acc[i][j], 0, 0, 0);
        }
        if (t < 15) {
            asm volatile("s_waitcnt vmcnt(0)" ::: "memory");
            __syncthreads();
        }
    }

    __syncthreads();
    double s = 0.0, ss = 0.0;
#pragma unroll
    for (int i = 0; i < 3; ++i)
#pragma unroll
        for (int j = 0; j < 3; ++j)
#pragma unroll
            for (int r = 0; r < 4; ++r) {
                const double v = (double)acc[i][j][r];
                s += v; ss += v * v;
            }
    double* ls  = (double*)&smem[0][0];
    double* lss = ls + 256;
    ls[tid] = s; lss[tid] = ss;
    __syncthreads();
    for (int st = 128; st; st >>= 1) {
        if (tid < st) { ls[tid] += ls[tid + st]; lss[tid] += lss[tid + st]; }
        __syncthreads();
    }
    if (tid == 0) {
        const int bf_ = ((b * FK + p) << 2) + blockIdx.x;
        part[2 * bf_]     = ls[0];
        part[2 * bf_ + 1] = lss[0];
    }

    float* ap = attnT + (size_t)(b * FK + p) * C * C;
#pragma unroll
    for (int i = 0; i < 3; ++i) {
        const int c0 = cf * 96 + wp * 48 + i * 16 + kg * 4;
#pragma unroll
        for (int j = 0; j < 3; ++j) {
            const int o = of * 96 + wq * 48 + j * 16 + ln15;
            *(f32x4*)(ap + o * C + c0) = acc[i][j];
        }
    }
}

__global__ __launch_bounds__(256) void finalize_k(const double* __restrict__ part,
                                                  const float* __restrict__ momp,
                                                  float* __restrict__ scal) {
    __shared__ double ls[256], lss[256];
    double s = 0.0, ss = 0.0;
    for (int i = threadIdx.x; i < 288; i += 256) {
        s += part[2 * i]; ss += part[2 * i + 1];
    }
    ls[threadIdx.x] = s; lss[threadIdx.x] = ss;
    __syncthreads();
    for (int st = 128; st; st >>= 1) {
        if (threadIdx.x < st) {
            ls[threadIdx.x]  += ls[threadIdx.x + st];
            lss[threadIdx.x] += lss[threadIdx.x + st];
        }
        __syncthreads();
    }
    if (threadIdx.x == 0) {
        const double n    = (double)(B * FK * C * C);
        const double mean = ls[0] / n;
        double var        = (lss[0] - ls[0] * ls[0] / n) / (n - 1.0);
        if (var < 0.0) var = 0.0;
        const double scale = 1.0 / (sqrt(var) + 1e-4);
        scal[0] = (float)((double)momp[0] + scale);  // alpha
        scal[1] = (float)(-mean * scale);            // beta
    }
}

// ---------------------------------------------------------------------------
// normW packed: out[b][chunk][lane][t] = bf16(alpha*attnT[b][p][co][ci]+beta)
// ---------------------------------------------------------------------------
__global__ __launch_bounds__(256) void norm_w(const float* __restrict__ attnT,
                                              const float* __restrict__ scal,
                                              unsigned short* __restrict__ o) {
    const float alpha = scal[0], beta = scal[1];
    const int g = (blockIdx.x * 256 + threadIdx.x) * 4;
    const int chunk = g >> 9, within = g & 511;
    const int lane = within >> 3, t0 = within & 7;
    const int cc = chunk % 6, c2 = chunk / 6;
    const int cot = c2 % 12, pb = c2 / 12;
    const int p = pb % FK, b = pb / FK;
    const int co = cot * 16 + (lane & 15);
    const int ci = cc * 32 + (lane >> 4) * 8 + t0;
    const float4 v = *(const float4*)(attnT + (((size_t)(b * FK + p) * C + co) * C + ci));
    s16x4 r;
    r[0] = (short)f2b(fmaf(alpha, v.x, beta));
    r[1] = (short)f2b(fmaf(alpha, v.y, beta));
    r[2] = (short)f2b(fmaf(alpha, v.z, beta));
    r[3] = (short)f2b(fmaf(alpha, v.w, beta));
    *(s16x4*)(o + g) = r;
}

} // anonymous namespace

extern "C" void kernel_launch(void* const* d_in, const int* in_sizes, int n_in,
                              void* d_out, int out_size, void* d_ws, size_t ws_size,
                              hipStream_t stream) {
    (void)in_sizes; (void)n_in; (void)out_size; (void)ws_size;
    const float* x1   = (const float*)d_in[0];
    const float* x2   = (const float*)d_in[1];
    const float* kw   = (const float*)d_in[2];
    const float* qw   = (const float*)d_in[3];
    const float* momp = (const float*)d_in[4];

    char* ws = (char*)d_ws;
    unsigned short* xpad1 = (unsigned short*)ws;                   // 29,503,488
    unsigned short* xpad2 = (unsigned short*)(ws + 29503488);      // 29,503,488
    unsigned short* kwA   = (unsigned short*)(ws + 59006976);      //    663,552
    unsigned short* qwA   = (unsigned short*)(ws + 59670528);      //    663,552
    unsigned short* kcS   = (unsigned short*)(ws + 60334080);      // 28,311,552
    float*          attnT = (float*)(ws + 88645632);               // 10,616,832
    double*         part  = (double*)(ws + 99262464);              //      4,608
    float*          scal  = (float*)(ws + 99278848);               //          8
    unsigned short* normW = kcS;            // kcS dead after attn; 5,308,416 B
    unsigned short* qcS   = (unsigned short*)d_out;  // scratch until final conv

    border_zero<<<582, 256, 0, stream>>>(xpad1);   // covers xpad1+xpad2 borders

    prep_x<<<dim3(3, 96, 16), 256, 0, stream>>>(x1, x2, xpad1);
    prep_w<<<2592, 256, 0, stream>>>(kw, qw, kwA, qwA);

    // both front convs in ONE dispatch (z: bit3 = tensor, low 3 bits = b)
    conv_mfma<false, false, true><<<dim3(24, 2, 16), 256, 0, stream>>>(
        xpad1, xpad2, kwA, qwA, kcS, qcS);

    attn_mfma<<<dim3(4, 9, 8), 256, 0, stream>>>(kcS, qcS, attnT, part);
    finalize_k<<<1, 256, 0, stream>>>(part, momp, scal);

    norm_w<<<2592, 256, 0, stream>>>(attnT, scal, normW);
    conv_mfma<true, true, false><<<dim3(24, 2, 8), 256, 0, stream>>>(
        xpad1, nullptr, normW, nullptr, (float*)d_out, nullptr);
}

// Round 12
// 248.684 us; speedup vs baseline: 3.2321x; 3.2321x over previous
//
#include <hip/hip_runtime.h>
#include <math.h>

typedef __attribute__((ext_vector_type(8))) short s16x8;
typedef __attribute__((ext_vector_type(4))) short s16x4;
typedef __attribute__((ext_vector_type(4))) float f32x4;

typedef unsigned int u32;
typedef __attribute__((address_space(3))) u32* lds_u32p;
typedef const __attribute__((address_space(1))) u32* glb_u32p;

namespace {

constexpr int B  = 8;
constexpr int C  = 192;
constexpr int H  = 96;
constexpr int W  = 96;
constexpr int FK = 9;
constexpr int HP = 98;    // padded
constexpr int L  = 1024;  // 32x32 patch grid per phase
constexpr int WCHUNK = FK * 12 * 6;          // 648 packed 1KB chunks per tensor
constexpr int WELEM  = WCHUNK * 512;         // 331776 bf16 elements
constexpr size_t XPAD_ELEMS = (size_t)B * HP * HP * 192;

__device__ inline unsigned short f2b(float f) {
    unsigned int x = __float_as_uint(f);
    x += 0x7fffu + ((x >> 16) & 1u);
    return (unsigned short)(x >> 16);
}

// ---------------------------------------------------------------------------
// zero ONLY the pad borders of both xpad tensors (replaces 59MB memset).
// ---------------------------------------------------------------------------
__global__ __launch_bounds__(256) void border_zero(unsigned short* __restrict__ xpad) {
    const int c   = blockIdx.x * 256 + threadIdx.x;
    const int c16 = c % 24;
    const int p_  = c / 24;
    const int pos = p_ % 388;
    const int bt  = p_ / 388;      // 0..15 spans xpad1 then xpad2
    int yy, xx;
    if (pos < 98)       { yy = 0;          xx = pos; }
    else if (pos < 196) { yy = 97;         xx = pos - 98; }
    else if (pos < 292) { yy = pos - 195;  xx = 0; }
    else                { yy = pos - 291;  xx = 97; }
    const size_t off = (((size_t)bt * HP + yy) * HP + xx) * 192 + c16 * 8;
    *(s16x8*)(xpad + off) = (s16x8){0, 0, 0, 0, 0, 0, 0, 0};
}

// ---------------------------------------------------------------------------
// x[b][c][96][96] f32 -> xpadT[b][98][98][192] bf16 (both tensors, z=16)
// ---------------------------------------------------------------------------
__global__ __launch_bounds__(256) void prep_x(const float* __restrict__ x1,
                                              const float* __restrict__ x2,
                                              unsigned short* __restrict__ xpadT) {
    __shared__ float xs[192][33];
    const int tid = threadIdx.x;
    const int x0  = blockIdx.x * 32;
    const int y   = blockIdx.y;
    const int zz  = blockIdx.z;
    const int b   = zz & 7, t = zz >> 3;
    const float* x = t ? x2 : x1;
    unsigned short* dst = xpadT + (size_t)t * XPAD_ELEMS;
    for (int e = tid; e < 192 * 32; e += 256) {
        const int ci = e >> 5, xx = e & 31;
        xs[ci][xx] = x[(((size_t)b * C + ci) * H + y) * W + x0 + xx];
    }
    __syncthreads();
    for (int e = tid; e < 32 * 192; e += 256) {
        const int pos = e / 192, ci = e - pos * 192;
        dst[(((size_t)(b * HP + y + 1)) * HP + x0 + pos + 1) * 192 + ci] = f2b(xs[ci][pos]);
    }
}

// ---------------------------------------------------------------------------
// pack weights into fragment-linear layout:
//   dst[(((p*12 + cot)*6 + cc))*512 + lane*8 + t]  = w[co][ci][p]
// ---------------------------------------------------------------------------
__global__ __launch_bounds__(256) void prep_w(const float* __restrict__ kw,
                                              const float* __restrict__ qw,
                                              unsigned short* __restrict__ kwA,
                                              unsigned short* __restrict__ qwA) {
    int idx = blockIdx.x * 256 + threadIdx.x;
    const float* src = kw;
    unsigned short* dst = kwA;
    if (idx >= WELEM) { idx -= WELEM; src = qw; dst = qwA; }
    const int chunk = idx >> 9, within = idx & 511;
    const int lane = within >> 3, t = within & 7;
    const int kg = lane >> 4, r15 = lane & 15;
    const int cc = chunk % 6, c2 = chunk / 6;
    const int cot = c2 % 12, p = c2 / 12;
    const int co = cot * 16 + r15;
    const int ci = cc * 32 + kg * 8 + t;
    dst[idx] = f2b(src[((size_t)co * C + ci) * FK + p]);
}

// ---------------------------------------------------------------------------
// FRONT conv (R8 structure, measured 142us merged, VGPR 84, no spill):
// 4 waves, wave = 48co x 48s x 1y; 2 x 19.2KB LDS dbuf; stage(dy+1) issued
// at cc==5 pinned by sched_barriers; batched 9-af per (dy,cc).
// DUAL: grid.z=16 encodes (tensor, b).
// ---------------------------------------------------------------------------
__global__ __launch_bounds__(256, 3)
void conv_front(const unsigned short* __restrict__ xpadA,
                const unsigned short* __restrict__ xpadB,
                const unsigned short* __restrict__ wA,
                const unsigned short* __restrict__ wB,
                void* __restrict__ youtA,
                void* __restrict__ youtB) {
    __shared__ __align__(16) char smem[2][19200];
    const int tid  = threadIdx.x;
    const int y    = blockIdx.x;
    const int sx   = blockIdx.y;        // s half (48 outputs)
    const int zz   = blockIdx.z;
    const int b    = zz & 7;
    const int t    = zz >> 3;
    const unsigned short* xpadT = t ? xpadB : xpadA;
    const unsigned short* wp    = t ? wB : wA;
    void* yout = t ? youtB : youtA;
    const int lane = tid & 63, wc = tid >> 6;
    const int ln15 = lane & 15, kg = lane >> 4;

    // staging: 50 pos x 24 chunks(16B) = 1200 chunks; 4 rounds + 176 tail
    int gfull[4];
#pragma unroll
    for (int it = 0; it < 4; ++it) {
        const int m = it * 256 + tid;
        const int q = m / 24, c16 = m - q * 24;
        gfull[it] = (sx * 48 + q) * 384 + ((c16 * 16) ^ ((q & 7) << 4));
    }
    int gtail = 0;
    if (tid < 176) {
        const int m = 1024 + tid;
        const int q = m / 24, c16 = m - q * 24;
        gtail = (sx * 48 + q) * 384 + ((c16 * 16) ^ ((q & 7) << 4));
    }

    auto stage = [&](char* lb, int prow) {
        const char* rowbase = (const char*)(xpadT + ((size_t)(b * HP + prow)) * HP * 192);
#pragma unroll
        for (int it = 0; it < 4; ++it)
            __builtin_amdgcn_global_load_lds(
                (glb_u32p)(const void*)(rowbase + gfull[it]),
                (lds_u32p)(void*)(lb + it * 4096 + wc * 1024), 16, 0, 0);
        if (tid < 176)
            __builtin_amdgcn_global_load_lds(
                (glb_u32p)(const void*)(rowbase + gtail),
                (lds_u32p)(void*)(lb + 16384 + wc * 1024), 16, 0, 0);
    };

    f32x4 acc[3][3];
#pragma unroll
    for (int i = 0; i < 3; ++i)
#pragma unroll
        for (int j = 0; j < 3; ++j)
            acc[i][j] = (f32x4){0.f, 0.f, 0.f, 0.f};

    stage(smem[0], y);

    for (int dy = 0; dy < 3; ++dy) {
        asm volatile("s_waitcnt vmcnt(0)" ::: "memory");  // stage of this buf done
        __syncthreads();
        const char* lb = smem[dy & 1];

#pragma unroll
        for (int cc = 0; cc < 6; ++cc) {
            s16x8 af[3][3];
#pragma unroll
            for (int dx = 0; dx < 3; ++dx)
#pragma unroll
                for (int i = 0; i < 3; ++i) {
                    const int chunkid = ((3 * dy + dx) * 12 + wc * 3 + i) * 6 + cc;
                    af[dx][i] = *(const s16x8*)(wp + (size_t)chunkid * 512 + lane * 8);
                }
            if (cc == 5) {
                __builtin_amdgcn_sched_barrier(0);   // af issues stay above
                if (dy < 2) stage((char*)smem[(dy + 1) & 1], y + dy + 1);
                __builtin_amdgcn_sched_barrier(0);   // stage issue pinned here
            }
            s16x8 bv[3][3];
#pragma unroll
            for (int j = 0; j < 3; ++j)
#pragma unroll
                for (int dx = 0; dx < 3; ++dx) {
                    const int q = j * 16 + ln15 + dx;
                    bv[j][dx] = *(const s16x8*)(lb + q * 384 +
                                    ((cc * 64 + kg * 16) ^ ((q & 7) << 4)));
                }
#pragma unroll
            for (int i = 0; i < 3; ++i)
#pragma unroll
                for (int j = 0; j < 3; ++j)
#pragma unroll
                    for (int dx = 0; dx < 3; ++dx)
                        acc[i][j] = __builtin_amdgcn_mfma_f32_16x16x32_bf16(
                            af[dx][i], bv[j][dx], acc[i][j], 0, 0, 0);
        }
    }

    // phase layout: dst[((b*9 + (y%3)*3 + s%3)*192 + co)*1024 + (y/3)*32 + s/3]
    unsigned short* yb = (unsigned short*)yout;
    const int ph = y % 3, lh = y / 3;
    int poff[3];
#pragma unroll
    for (int j = 0; j < 3; ++j) {
        const int s  = sx * 48 + j * 16 + ln15;
        const int pw = s % 3, lw = s / 3;
        poff[j] = ((b * FK + ph * 3 + pw) * C) * L + lh * 32 + lw;
    }
#pragma unroll
    for (int i = 0; i < 3; ++i)
#pragma unroll
        for (int rr = 0; rr < 4; ++rr) {
            const int co = wc * 48 + i * 16 + kg * 4 + rr;
#pragma unroll
            for (int j = 0; j < 3; ++j)
                yb[(size_t)poff[j] + co * L] = f2b(acc[i][j][rr]);
        }
}

// ---------------------------------------------------------------------------
// FINAL conv (R10 wide-s structure, no spill, VGPR 88): wave = 48co x 96s x 1y,
// per-batch normW weights (wide-s halves per-batch weight traffic). Full-row
// 37.6KB LDS staged per dy; dy/cc ROLLED; 3-af batch; plain launch_bounds(256).
// grid (96 y, 8 b).
// ---------------------------------------------------------------------------
__global__ __launch_bounds__(256)
void conv_final(const unsigned short* __restrict__ xpadT,
                const unsigned short* __restrict__ wA,
                float* __restrict__ yout) {
    __shared__ __align__(16) char smem[HP * 384];   // 37632 B
    const int tid  = threadIdx.x;
    const int y    = blockIdx.x;
    const int b    = blockIdx.y;
    const int lane = tid & 63, wc = tid >> 6;
    const int ln15 = lane & 15, kg = lane >> 4;

    const unsigned short* wp = wA + (size_t)b * WELEM;

    // staging: full row = 98 pos x 24 chunks(16B) = 2352; 9 rounds + 48 tail
    int gofs[9];
#pragma unroll
    for (int it = 0; it < 9; ++it) {
        const int m = it * 256 + tid;
        const int q = m / 24, c16 = m - q * 24;
        gofs[it] = q * 384 + ((c16 * 16) ^ ((q & 7) << 4));
    }
    int gtail = 0;
    if (tid < 48) {
        const int m = 2304 + tid;
        const int q = m / 24, c16 = m - q * 24;
        gtail = q * 384 + ((c16 * 16) ^ ((q & 7) << 4));
    }

    auto stage = [&](int prow) {
        const char* rb = (const char*)(xpadT + ((size_t)(b * HP + prow)) * HP * 192);
#pragma unroll
        for (int it = 0; it < 9; ++it)
            __builtin_amdgcn_global_load_lds(
                (glb_u32p)(const void*)(rb + gofs[it]),
                (lds_u32p)(void*)(smem + it * 4096 + wc * 1024), 16, 0, 0);
        if (tid < 48)
            __builtin_amdgcn_global_load_lds(
                (glb_u32p)(const void*)(rb + gtail),
                (lds_u32p)(void*)(smem + 36864 + wc * 1024), 16, 0, 0);
    };

    f32x4 acc[3][6];
#pragma unroll
    for (int i = 0; i < 3; ++i)
#pragma unroll
        for (int j = 0; j < 6; ++j)
            acc[i][j] = (f32x4){0.f, 0.f, 0.f, 0.f};

    stage(y);

#pragma unroll 1
    for (int dy = 0; dy < 3; ++dy) {
        asm volatile("s_waitcnt vmcnt(0)" ::: "memory");
        __syncthreads();

#pragma unroll 1
        for (int cc = 0; cc < 6; ++cc) {
#pragma unroll
            for (int dx = 0; dx < 3; ++dx) {
                const int cid = (((3 * dy + dx) * 12 + wc * 3) * 6 + cc);
                const s16x8 af0 = *(const s16x8*)(wp + (size_t)cid * 512 + lane * 8);
                const s16x8 af1 = *(const s16x8*)(wp + (size_t)(cid + 6) * 512 + lane * 8);
                const s16x8 af2 = *(const s16x8*)(wp + (size_t)(cid + 12) * 512 + lane * 8);
#pragma unroll
                for (int j = 0; j < 6; ++j) {
                    const int q = j * 16 + ln15 + dx;
                    const s16x8 bv = *(const s16x8*)(smem + q * 384 +
                                        ((cc * 64 + kg * 16) ^ ((q & 7) << 4)));
                    acc[0][j] = __builtin_amdgcn_mfma_f32_16x16x32_bf16(af0, bv, acc[0][j], 0, 0, 0);
                    acc[1][j] = __builtin_amdgcn_mfma_f32_16x16x32_bf16(af1, bv, acc[1][j], 0, 0, 0);
                    acc[2][j] = __builtin_amdgcn_mfma_f32_16x16x32_bf16(af2, bv, acc[2][j], 0, 0, 0);
                }
            }
        }
        if (dy < 2) {
            __syncthreads();          // all waves done reading smem
            stage(y + dy + 1);
        }
    }

#pragma unroll
    for (int i = 0; i < 3; ++i)
#pragma unroll
        for (int rr = 0; rr < 4; ++rr) {
            const int co = wc * 48 + i * 16 + kg * 4 + rr;
            const size_t base = (((size_t)b * C + co) * H + y) * W;
#pragma unroll
            for (int j = 0; j < 6; ++j)
                yout[base + j * 16 + ln15] = acc[i][j][rr];
        }
}

// ---------------------------------------------------------------------------
// attn MFMA: per (b,phase) GEMM D[c][o] = sum_k Kc[c][k]*Qc[o][k], K=1024.
// Block = 96c x 96o quarter, 4 waves 48x48. BK=64 double-buffered staging.
// Epilogue: attnT[b][p][o][c] f32 + fused f64 sum/ssq partials.
// ---------------------------------------------------------------------------
__global__ __launch_bounds__(256, 3)
void attn_mfma(const unsigned short* __restrict__ kcS,
               const unsigned short* __restrict__ qcS,
               float* __restrict__ attnT,
               double* __restrict__ part) {
    __shared__ __align__(16) char smem[2][24576];   // [buf][A 12KB | B 12KB]
    const int tid  = threadIdx.x;
    const int lane = tid & 63, wid = tid >> 6;
    const int wq   = wid & 1, wp = wid >> 1;
    const int ln15 = lane & 15, kg = lane >> 4;
    const int of   = blockIdx.x & 1, cf = blockIdx.x >> 1;
    const int p    = blockIdx.y, b = blockIdx.z;

    const char* Abase = (const char*)(kcS + ((size_t)(b * FK + p) * C + cf * 96) * L);
    const char* Bbase = (const char*)(qcS + ((size_t)(b * FK + p) * C + of * 96) * L);

    int gofs[3];
#pragma unroll
    for (int it = 0; it < 3; ++it) {
        const int chunk = it * 256 + tid;
        const int row = chunk >> 3, c16 = chunk & 7;
        gofs[it] = row * 2048 + ((c16 * 16) ^ ((row & 7) << 4));
    }

    auto stage = [&](int bufi, int t) {
        const char* Ab = Abase + t * 128;
        const char* Bb = Bbase + t * 128;
        char* lb = (char*)smem[bufi];
#pragma unroll
        for (int it = 0; it < 3; ++it)
            __builtin_amdgcn_global_load_lds(
                (glb_u32p)(const void*)(Ab + gofs[it]),
                (lds_u32p)(void*)(lb + it * 4096 + wid * 1024), 16, 0, 0);
#pragma unroll
        for (int it = 0; it < 3; ++it)
            __builtin_amdgcn_global_load_lds(
                (glb_u32p)(const void*)(Bb + gofs[it]),
                (lds_u32p)(void*)(lb + 12288 + it * 4096 + wid * 1024), 16, 0, 0);
    };

    f32x4 acc[3][3];
#pragma unroll
    for (int i = 0; i < 3; ++i)
#pragma unroll
        for (int j = 0; j < 3; ++j)
            acc[i][j] = (f32x4){0.f, 0.f, 0.f, 0.f};

    stage(0, 0);
    asm volatile("s_waitcnt vmcnt(0)" ::: "memory");
    __syncthreads();

    for (int t = 0; t < 16; ++t) {
        if (t < 15) stage((t + 1) & 1, t + 1);
        const char* lb = (const char*)smem[t & 1];
#pragma unroll
        for (int ks = 0; ks < 2; ++ks) {
            s16x8 af[3], bf[3];
#pragma unroll
            for (int i = 0; i < 3; ++i) {
                const int row = wp * 48 + i * 16 + ln15;
                af[i] = *(const s16x8*)(lb + row * 128 +
                                        ((ks * 64 + kg * 16) ^ ((row & 7) << 4)));
            }
#pragma unroll
            for (int j = 0; j < 3; ++j) {
                const int row = wq * 48 + j * 16 + ln15;
                bf[j] = *(const s16x8*)(lb + 12288 + row * 128 +
                                        ((ks * 64 + kg * 16) ^ ((row & 7) << 4)));
            }
#pragma unroll
            for (int i = 0; i < 3; ++i)
#pragma unroll
                for (int j = 0; j < 3; ++j)
                    acc[i][j] = __builtin_amdgcn_mfma_f32_16x16x32_bf16(
                        af[i], bf[j], acc[i][j], 0, 0, 0);
        }
        if (t < 15) {
            asm volatile("s_waitcnt vmcnt(0)" ::: "memory");
            __syncthreads();
        }
    }

    __syncthreads();
    double s = 0.0, ss = 0.0;
#pragma unroll
    for (int i = 0; i < 3; ++i)
#pragma unroll
        for (int j = 0; j < 3; ++j)
#pragma unroll
            for (int r = 0; r < 4; ++r) {
                const double v = (double)acc[i][j][r];
                s += v; ss += v * v;
            }
    double* ls  = (double*)&smem[0][0];
    double* lss = ls + 256;
    ls[tid] = s; lss[tid] = ss;
    __syncthreads();
    for (int st = 128; st; st >>= 1) {
        if (tid < st) { ls[tid] += ls[tid + st]; lss[tid] += lss[tid + st]; }
        __syncthreads();
    }
    if (tid == 0) {
        const int bf_ = ((b * FK + p) << 2) + blockIdx.x;
        part[2 * bf_]     = ls[0];
        part[2 * bf_ + 1] = lss[0];
    }

    float* ap = attnT + (size_t)(b * FK + p) * C * C;
#pragma unroll
    for (int i = 0; i < 3; ++i) {
        const int c0 = cf * 96 + wp * 48 + i * 16 + kg * 4;
#pragma unroll
        for (int j = 0; j < 3; ++j) {
            const int o = of * 96 + wq * 48 + j * 16 + ln15;
            *(f32x4*)(ap + o * C + c0) = acc[i][j];
        }
    }
}

__global__ __launch_bounds__(256) void finalize_k(const double* __restrict__ part,
                                                  const float* __restrict__ momp,
                                                  float* __restrict__ scal) {
    __shared__ double ls[256], lss[256];
    double s = 0.0, ss = 0.0;
    for (int i = threadIdx.x; i < 288; i += 256) {
        s += part[2 * i]; ss += part[2 * i + 1];
    }
    ls[threadIdx.x] = s; lss[threadIdx.x] = ss;
    __syncthreads();
    for (int st = 128; st; st >>= 1) {
        if (threadIdx.x < st) {
            ls[threadIdx.x]  += ls[threadIdx.x + st];
            lss[threadIdx.x] += lss[threadIdx.x + st];
        }
        __syncthreads();
    }
    if (threadIdx.x == 0) {
        const double n    = (double)(B * FK * C * C);
        const double mean = ls[0] / n;
        double var        = (lss[0] - ls[0] * ls[0] / n) / (n - 1.0);
        if (var < 0.0) var = 0.0;
        const double scale = 1.0 / (sqrt(var) + 1e-4);
        scal[0] = (float)((double)momp[0] + scale);  // alpha
        scal[1] = (float)(-mean * scale);            // beta
    }
}

// ---------------------------------------------------------------------------
// normW packed: out[b][chunk][lane][t] = bf16(alpha*attnT[b][p][co][ci]+beta)
// ---------------------------------------------------------------------------
__global__ __launch_bounds__(256) void norm_w(const float* __restrict__ attnT,
                                              const float* __restrict__ scal,
                                              unsigned short* __restrict__ o) {
    const float alpha = scal[0], beta = scal[1];
    const int g = (blockIdx.x * 256 + threadIdx.x) * 4;
    const int chunk = g >> 9, within = g & 511;
    const int lane = within >> 3, t0 = within & 7;
    const int cc = chunk % 6, c2 = chunk / 6;
    const int cot = c2 % 12, pb = c2 / 12;
    const int p = pb % FK, b = pb / FK;
    const int co = cot * 16 + (lane & 15);
    const int ci = cc * 32 + (lane >> 4) * 8 + t0;
    const float4 v = *(const float4*)(attnT + (((size_t)(b * FK + p) * C + co) * C + ci));
    s16x4 r;
    r[0] = (short)f2b(fmaf(alpha, v.x, beta));
    r[1] = (short)f2b(fmaf(alpha, v.y, beta));
    r[2] = (short)f2b(fmaf(alpha, v.z, beta));
    r[3] = (short)f2b(fmaf(alpha, v.w, beta));
    *(s16x4*)(o + g) = r;
}

} // anonymous namespace

extern "C" void kernel_launch(void* const* d_in, const int* in_sizes, int n_in,
                              void* d_out, int out_size, void* d_ws, size_t ws_size,
                              hipStream_t stream) {
    (void)in_sizes; (void)n_in; (void)out_size; (void)ws_size;
    const float* x1   = (const float*)d_in[0];
    const float* x2   = (const float*)d_in[1];
    const float* kw   = (const float*)d_in[2];
    const float* qw   = (const float*)d_in[3];
    const float* momp = (const float*)d_in[4];

    char* ws = (char*)d_ws;
    unsigned short* xpad1 = (unsigned short*)ws;                   // 29,503,488
    unsigned short* xpad2 = (unsigned short*)(ws + 29503488);      // 29,503,488
    unsigned short* kwA   = (unsigned short*)(ws + 59006976);      //    663,552
    unsigned short* qwA   = (unsigned short*)(ws + 59670528);      //    663,552
    unsigned short* kcS   = (unsigned short*)(ws + 60334080);      // 28,311,552
    float*          attnT = (float*)(ws + 88645632);               // 10,616,832
    double*         part  = (double*)(ws + 99262464);              //      4,608
    float*          scal  = (float*)(ws + 99278848);               //          8
    unsigned short* normW = kcS;            // kcS dead after attn; 5,308,416 B
    unsigned short* qcS   = (unsigned short*)d_out;  // scratch until final conv

    border_zero<<<582, 256, 0, stream>>>(xpad1);   // covers xpad1+xpad2 borders

    prep_x<<<dim3(3, 96, 16), 256, 0, stream>>>(x1, x2, xpad1);
    prep_w<<<2592, 256, 0, stream>>>(kw, qw, kwA, qwA);

    // both front convs in ONE dispatch (z: bit3 = tensor, low 3 bits = b)
    conv_front<<<dim3(96, 2, 16), 256, 0, stream>>>(
        xpad1, xpad2, kwA, qwA, kcS, qcS);

    attn_mfma<<<dim3(4, 9, 8), 256, 0, stream>>>(kcS, qcS, attnT, part);
    finalize_k<<<1, 256, 0, stream>>>(part, momp, scal);

    norm_w<<<2592, 256, 0, stream>>>(attnT, scal, normW);
    conv_final<<<dim3(96, 8), 256, 0, stream>>>(xpad1, normW, (float*)d_out);
}

// Round 13
// 240.217 us; speedup vs baseline: 3.3460x; 1.0352x over previous
//
#include <hip/hip_runtime.h>
#include <math.h>

typedef __attribute__((ext_vector_type(8))) short s16x8;
typedef __attribute__((ext_vector_type(4))) short s16x4;
typedef __attribute__((ext_vector_type(4))) float f32x4;

typedef unsigned int u32;
typedef __attribute__((address_space(3))) u32* lds_u32p;
typedef const __attribute__((address_space(1))) u32* glb_u32p;

namespace {

constexpr int B  = 8;
constexpr int C  = 192;
constexpr int H  = 96;
constexpr int W  = 96;
constexpr int FK = 9;
constexpr int HP = 98;    // padded
constexpr int L  = 1024;  // 32x32 patch grid per phase
constexpr int WCHUNK = FK * 12 * 6;          // 648 packed 1KB chunks per tensor
constexpr int WELEM  = WCHUNK * 512;         // 331776 bf16 elements
constexpr size_t XPAD_ELEMS = (size_t)B * HP * HP * 192;

__device__ inline unsigned short f2b(float f) {
    unsigned int x = __float_as_uint(f);
    x += 0x7fffu + ((x >> 16) & 1u);
    return (unsigned short)(x >> 16);
}

// ---------------------------------------------------------------------------
// MERGED prep: [0,4608) prep_x (x->xpadT bf16 channel-last, both tensors),
// [4608,7200) prep_w (fragment-linear weight pack, both tensors),
// [7200,7782) border_zero (zero pad borders of both xpad tensors).
// All regions disjoint; one dispatch replaces three.
// ---------------------------------------------------------------------------
__global__ __launch_bounds__(256) void prep_all(const float* __restrict__ x1,
                                                const float* __restrict__ x2,
                                                const float* __restrict__ kw,
                                                const float* __restrict__ qw,
                                                unsigned short* __restrict__ xpadT,
                                                unsigned short* __restrict__ kwA,
                                                unsigned short* __restrict__ qwA) {
    __shared__ float xs[192][33];
    const int gid = blockIdx.x;
    const int tid = threadIdx.x;

    if (gid < 4608) {
        // ---- prep_x: grid (3 xtiles, 96 y, 16 zz) linearized ----
        const int bx = gid % 3, by = (gid / 3) % 96, bz = gid / 288;
        const int x0 = bx * 32, y = by;
        const int b = bz & 7, t = bz >> 3;
        const float* x = t ? x2 : x1;
        unsigned short* dst = xpadT + (size_t)t * XPAD_ELEMS;
        for (int e = tid; e < 192 * 32; e += 256) {
            const int ci = e >> 5, xx = e & 31;
            xs[ci][xx] = x[(((size_t)b * C + ci) * H + y) * W + x0 + xx];
        }
        __syncthreads();
        for (int e = tid; e < 32 * 192; e += 256) {
            const int pos = e / 192, ci = e - pos * 192;
            dst[(((size_t)(b * HP + y + 1)) * HP + x0 + pos + 1) * 192 + ci] =
                f2b(xs[ci][pos]);
        }
    } else if (gid < 7200) {
        // ---- prep_w ----
        int idx = (gid - 4608) * 256 + tid;
        const float* src = kw;
        unsigned short* dst = kwA;
        if (idx >= WELEM) { idx -= WELEM; src = qw; dst = qwA; }
        const int chunk = idx >> 9, within = idx & 511;
        const int lane = within >> 3, t = within & 7;
        const int kg = lane >> 4, r15 = lane & 15;
        const int cc = chunk % 6, c2 = chunk / 6;
        const int cot = c2 % 12, p = c2 / 12;
        const int co = cot * 16 + r15;
        const int ci = cc * 32 + kg * 8 + t;
        dst[idx] = f2b(src[((size_t)co * C + ci) * FK + p]);
    } else {
        // ---- border_zero: both xpad tensors ----
        const int c   = (gid - 7200) * 256 + tid;
        const int c16 = c % 24;
        const int p_  = c / 24;
        const int pos = p_ % 388;
        const int bt  = p_ / 388;      // 0..15 spans xpad1 then xpad2
        int yy, xx;
        if (pos < 98)       { yy = 0;          xx = pos; }
        else if (pos < 196) { yy = 97;         xx = pos - 98; }
        else if (pos < 292) { yy = pos - 195;  xx = 0; }
        else                { yy = pos - 291;  xx = 97; }
        const size_t off = (((size_t)bt * HP + yy) * HP + xx) * 192 + c16 * 8;
        *(s16x8*)(xpadT + off) = (s16x8){0, 0, 0, 0, 0, 0, 0, 0};
    }
}

// ---------------------------------------------------------------------------
// FRONT conv (R8 structure, measured 142us merged, VGPR 84, no spill):
// 4 waves, wave = 48co x 48s x 1y; 2 x 19.2KB LDS dbuf; stage(dy+1) issued
// at cc==5 pinned by sched_barriers; batched 9-af per (dy,cc).
// DUAL: grid.z=16 encodes (tensor, b).
// ---------------------------------------------------------------------------
__global__ __launch_bounds__(256, 3)
void conv_front(const unsigned short* __restrict__ xpadA,
                const unsigned short* __restrict__ xpadB,
                const unsigned short* __restrict__ wA,
                const unsigned short* __restrict__ wB,
                void* __restrict__ youtA,
                void* __restrict__ youtB) {
    __shared__ __align__(16) char smem[2][19200];
    const int tid  = threadIdx.x;
    const int y    = blockIdx.x;
    const int sx   = blockIdx.y;        // s half (48 outputs)
    const int zz   = blockIdx.z;
    const int b    = zz & 7;
    const int t    = zz >> 3;
    const unsigned short* xpadT = t ? xpadB : xpadA;
    const unsigned short* wp    = t ? wB : wA;
    void* yout = t ? youtB : youtA;
    const int lane = tid & 63, wc = tid >> 6;
    const int ln15 = lane & 15, kg = lane >> 4;

    // staging: 50 pos x 24 chunks(16B) = 1200 chunks; 4 rounds + 176 tail
    int gfull[4];
#pragma unroll
    for (int it = 0; it < 4; ++it) {
        const int m = it * 256 + tid;
        const int q = m / 24, c16 = m - q * 24;
        gfull[it] = (sx * 48 + q) * 384 + ((c16 * 16) ^ ((q & 7) << 4));
    }
    int gtail = 0;
    if (tid < 176) {
        const int m = 1024 + tid;
        const int q = m / 24, c16 = m - q * 24;
        gtail = (sx * 48 + q) * 384 + ((c16 * 16) ^ ((q & 7) << 4));
    }

    auto stage = [&](char* lb, int prow) {
        const char* rowbase = (const char*)(xpadT + ((size_t)(b * HP + prow)) * HP * 192);
#pragma unroll
        for (int it = 0; it < 4; ++it)
            __builtin_amdgcn_global_load_lds(
                (glb_u32p)(const void*)(rowbase + gfull[it]),
                (lds_u32p)(void*)(lb + it * 4096 + wc * 1024), 16, 0, 0);
        if (tid < 176)
            __builtin_amdgcn_global_load_lds(
                (glb_u32p)(const void*)(rowbase + gtail),
                (lds_u32p)(void*)(lb + 16384 + wc * 1024), 16, 0, 0);
    };

    f32x4 acc[3][3];
#pragma unroll
    for (int i = 0; i < 3; ++i)
#pragma unroll
        for (int j = 0; j < 3; ++j)
            acc[i][j] = (f32x4){0.f, 0.f, 0.f, 0.f};

    stage(smem[0], y);

    for (int dy = 0; dy < 3; ++dy) {
        asm volatile("s_waitcnt vmcnt(0)" ::: "memory");  // stage of this buf done
        __syncthreads();
        const char* lb = smem[dy & 1];

#pragma unroll
        for (int cc = 0; cc < 6; ++cc) {
            s16x8 af[3][3];
#pragma unroll
            for (int dx = 0; dx < 3; ++dx)
#pragma unroll
                for (int i = 0; i < 3; ++i) {
                    const int chunkid = ((3 * dy + dx) * 12 + wc * 3 + i) * 6 + cc;
                    af[dx][i] = *(const s16x8*)(wp + (size_t)chunkid * 512 + lane * 8);
                }
            if (cc == 5) {
                __builtin_amdgcn_sched_barrier(0);   // af issues stay above
                if (dy < 2) stage((char*)smem[(dy + 1) & 1], y + dy + 1);
                __builtin_amdgcn_sched_barrier(0);   // stage issue pinned here
            }
            s16x8 bv[3][3];
#pragma unroll
            for (int j = 0; j < 3; ++j)
#pragma unroll
                for (int dx = 0; dx < 3; ++dx) {
                    const int q = j * 16 + ln15 + dx;
                    bv[j][dx] = *(const s16x8*)(lb + q * 384 +
                                    ((cc * 64 + kg * 16) ^ ((q & 7) << 4)));
                }
#pragma unroll
            for (int i = 0; i < 3; ++i)
#pragma unroll
                for (int j = 0; j < 3; ++j)
#pragma unroll
                    for (int dx = 0; dx < 3; ++dx)
                        acc[i][j] = __builtin_amdgcn_mfma_f32_16x16x32_bf16(
                            af[dx][i], bv[j][dx], acc[i][j], 0, 0, 0);
        }
    }

    // phase layout: dst[((b*9 + (y%3)*3 + s%3)*192 + co)*1024 + (y/3)*32 + s/3]
    unsigned short* yb = (unsigned short*)yout;
    const int ph = y % 3, lh = y / 3;
    int poff[3];
#pragma unroll
    for (int j = 0; j < 3; ++j) {
        const int s  = sx * 48 + j * 16 + ln15;
        const int pw = s % 3, lw = s / 3;
        poff[j] = ((b * FK + ph * 3 + pw) * C) * L + lh * 32 + lw;
    }
#pragma unroll
    for (int i = 0; i < 3; ++i)
#pragma unroll
        for (int rr = 0; rr < 4; ++rr) {
            const int co = wc * 48 + i * 16 + kg * 4 + rr;
#pragma unroll
            for (int j = 0; j < 3; ++j)
                yb[(size_t)poff[j] + co * L] = f2b(acc[i][j][rr]);
        }
}

// ---------------------------------------------------------------------------
// FINAL conv (R10 wide-s structure, no spill, VGPR 88): wave = 48co x 96s x 1y,
// per-batch normW weights. Full-row 37.6KB LDS staged per dy; dy/cc ROLLED;
// 3-af batch; plain launch_bounds(256).
// XCD-batch affinity: grid 1-D 768, b = id&7 (linear wg id round-robins XCDs
// -> each XCD runs one batch's 96 blocks; its 5.3MB normW stays in own L2).
// ---------------------------------------------------------------------------
__global__ __launch_bounds__(256)
void conv_final(const unsigned short* __restrict__ xpadT,
                const unsigned short* __restrict__ wA,
                float* __restrict__ yout) {
    __shared__ __align__(16) char smem[HP * 384];   // 37632 B
    const int tid  = threadIdx.x;
    const int b    = blockIdx.x & 7;    // XCD id on 8-XCD dispatch
    const int y    = blockIdx.x >> 3;
    const int lane = tid & 63, wc = tid >> 6;
    const int ln15 = lane & 15, kg = lane >> 4;

    const unsigned short* wp = wA + (size_t)b * WELEM;

    // staging: full row = 98 pos x 24 chunks(16B) = 2352; 9 rounds + 48 tail
    int gofs[9];
#pragma unroll
    for (int it = 0; it < 9; ++it) {
        const int m = it * 256 + tid;
        const int q = m / 24, c16 = m - q * 24;
        gofs[it] = q * 384 + ((c16 * 16) ^ ((q & 7) << 4));
    }
    int gtail = 0;
    if (tid < 48) {
        const int m = 2304 + tid;
        const int q = m / 24, c16 = m - q * 24;
        gtail = q * 384 + ((c16 * 16) ^ ((q & 7) << 4));
    }

    auto stage = [&](int prow) {
        const char* rb = (const char*)(xpadT + ((size_t)(b * HP + prow)) * HP * 192);
#pragma unroll
        for (int it = 0; it < 9; ++it)
            __builtin_amdgcn_global_load_lds(
                (glb_u32p)(const void*)(rb + gofs[it]),
                (lds_u32p)(void*)(smem + it * 4096 + wc * 1024), 16, 0, 0);
        if (tid < 48)
            __builtin_amdgcn_global_load_lds(
                (glb_u32p)(const void*)(rb + gtail),
                (lds_u32p)(void*)(smem + 36864 + wc * 1024), 16, 0, 0);
    };

    f32x4 acc[3][6];
#pragma unroll
    for (int i = 0; i < 3; ++i)
#pragma unroll
        for (int j = 0; j < 6; ++j)
            acc[i][j] = (f32x4){0.f, 0.f, 0.f, 0.f};

    stage(y);

#pragma unroll 1
    for (int dy = 0; dy < 3; ++dy) {
        asm volatile("s_waitcnt vmcnt(0)" ::: "memory");
        __syncthreads();

#pragma unroll 1
        for (int cc = 0; cc < 6; ++cc) {
#pragma unroll
            for (int dx = 0; dx < 3; ++dx) {
                const int cid = (((3 * dy + dx) * 12 + wc * 3) * 6 + cc);
                const s16x8 af0 = *(const s16x8*)(wp + (size_t)cid * 512 + lane * 8);
                const s16x8 af1 = *(const s16x8*)(wp + (size_t)(cid + 6) * 512 + lane * 8);
                const s16x8 af2 = *(const s16x8*)(wp + (size_t)(cid + 12) * 512 + lane * 8);
#pragma unroll
                for (int j = 0; j < 6; ++j) {
                    const int q = j * 16 + ln15 + dx;
                    const s16x8 bv = *(const s16x8*)(smem + q * 384 +
                                        ((cc * 64 + kg * 16) ^ ((q & 7) << 4)));
                    acc[0][j] = __builtin_amdgcn_mfma_f32_16x16x32_bf16(af0, bv, acc[0][j], 0, 0, 0);
                    acc[1][j] = __builtin_amdgcn_mfma_f32_16x16x32_bf16(af1, bv, acc[1][j], 0, 0, 0);
                    acc[2][j] = __builtin_amdgcn_mfma_f32_16x16x32_bf16(af2, bv, acc[2][j], 0, 0, 0);
                }
            }
        }
        if (dy < 2) {
            __syncthreads();          // all waves done reading smem
            stage(y + dy + 1);
        }
    }

#pragma unroll
    for (int i = 0; i < 3; ++i)
#pragma unroll
        for (int rr = 0; rr < 4; ++rr) {
            const int co = wc * 48 + i * 16 + kg * 4 + rr;
            const size_t base = (((size_t)b * C + co) * H + y) * W;
#pragma unroll
            for (int j = 0; j < 6; ++j)
                yout[base + j * 16 + ln15] = acc[i][j][rr];
        }
}

// ---------------------------------------------------------------------------
// attn MFMA: per (b,phase) GEMM D[c][o] = sum_k Kc[c][k]*Qc[o][k], K=1024.
// Block = 96c x 96o quarter, 4 waves 48x48. BK=64 double-buffered staging.
// Epilogue: attnT[b][p][o][c] f32 + fused f64 sum/ssq partials.
// ---------------------------------------------------------------------------
__global__ __launch_bounds__(256, 3)
void attn_mfma(const unsigned short* __restrict__ kcS,
               const unsigned short* __restrict__ qcS,
               float* __restrict__ attnT,
               double* __restrict__ part) {
    __shared__ __align__(16) char smem[2][24576];   // [buf][A 12KB | B 12KB]
    const int tid  = threadIdx.x;
    const int lane = tid & 63, wid = tid >> 6;
    const int wq   = wid & 1, wp = wid >> 1;
    const int ln15 = lane & 15, kg = lane >> 4;
    const int of   = blockIdx.x & 1, cf = blockIdx.x >> 1;
    const int p    = blockIdx.y, b = blockIdx.z;

    const char* Abase = (const char*)(kcS + ((size_t)(b * FK + p) * C + cf * 96) * L);
    const char* Bbase = (const char*)(qcS + ((size_t)(b * FK + p) * C + of * 96) * L);

    int gofs[3];
#pragma unroll
    for (int it = 0; it < 3; ++it) {
        const int chunk = it * 256 + tid;
        const int row = chunk >> 3, c16 = chunk & 7;
        gofs[it] = row * 2048 + ((c16 * 16) ^ ((row & 7) << 4));
    }

    auto stage = [&](int bufi, int t) {
        const char* Ab = Abase + t * 128;
        const char* Bb = Bbase + t * 128;
        char* lb = (char*)smem[bufi];
#pragma unroll
        for (int it = 0; it < 3; ++it)
            __builtin_amdgcn_global_load_lds(
                (glb_u32p)(const void*)(Ab + gofs[it]),
                (lds_u32p)(void*)(lb + it * 4096 + wid * 1024), 16, 0, 0);
#pragma unroll
        for (int it = 0; it < 3; ++it)
            __builtin_amdgcn_global_load_lds(
                (glb_u32p)(const void*)(Bb + gofs[it]),
                (lds_u32p)(void*)(lb + 12288 + it * 4096 + wid * 1024), 16, 0, 0);
    };

    f32x4 acc[3][3];
#pragma unroll
    for (int i = 0; i < 3; ++i)
#pragma unroll
        for (int j = 0; j < 3; ++j)
            acc[i][j] = (f32x4){0.f, 0.f, 0.f, 0.f};

    stage(0, 0);
    asm volatile("s_waitcnt vmcnt(0)" ::: "memory");
    __syncthreads();

    for (int t = 0; t < 16; ++t) {
        if (t < 15) stage((t + 1) & 1, t + 1);
        const char* lb = (const char*)smem[t & 1];
#pragma unroll
        for (int ks = 0; ks < 2; ++ks) {
            s16x8 af[3], bf[3];
#pragma unroll
            for (int i = 0; i < 3; ++i) {
                const int row = wp * 48 + i * 16 + ln15;
                af[i] = *(const s16x8*)(lb + row * 128 +
                                        ((ks * 64 + kg * 16) ^ ((row & 7) << 4)));
            }
#pragma unroll
            for (int j = 0; j < 3; ++j) {
                const int row = wq * 48 + j * 16 + ln15;
                bf[j] = *(const s16x8*)(lb + 12288 + row * 128 +
                                        ((ks * 64 + kg * 16) ^ ((row & 7) << 4)));
            }
#pragma unroll
            for (int i = 0; i < 3; ++i)
#pragma unroll
                for (int j = 0; j < 3; ++j)
                    acc[i][j] = __builtin_amdgcn_mfma_f32_16x16x32_bf16(
                        af[i], bf[j], acc[i][j], 0, 0, 0);
        }
        if (t < 15) {
            asm volatile("s_waitcnt vmcnt(0)" ::: "memory");
            __syncthreads();
        }
    }

    __syncthreads();
    double s = 0.0, ss = 0.0;
#pragma unroll
    for (int i = 0; i < 3; ++i)
#pragma unroll
        for (int j = 0; j < 3; ++j)
#pragma unroll
            for (int r = 0; r < 4; ++r) {
                const double v = (double)acc[i][j][r];
                s += v; ss += v * v;
            }
    double* ls  = (double*)&smem[0][0];
    double* lss = ls + 256;
    ls[tid] = s; lss[tid] = ss;
    __syncthreads();
    for (int st = 128; st; st >>= 1) {
        if (tid < st) { ls[tid] += ls[tid + st]; lss[tid] += lss[tid + st]; }
        __syncthreads();
    }
    if (tid == 0) {
        const int bf_ = ((b * FK + p) << 2) + blockIdx.x;
        part[2 * bf_]     = ls[0];
        part[2 * bf_ + 1] = lss[0];
    }

    float* ap = attnT + (size_t)(b * FK + p) * C * C;
#pragma unroll
    for (int i = 0; i < 3; ++i) {
        const int c0 = cf * 96 + wp * 48 + i * 16 + kg * 4;
#pragma unroll
        for (int j = 0; j < 3; ++j) {
            const int o = of * 96 + wq * 48 + j * 16 + ln15;
            *(f32x4*)(ap + o * C + c0) = acc[i][j];
        }
    }
}

// ---------------------------------------------------------------------------
// normW packed + INLINE finalize: every block redundantly reduces the 288
// f64 partial pairs (4.6KB, L2-hot, deterministic) -> alpha/beta, then
// out[b][chunk][lane][t] = bf16(alpha*attnT[b][p][co][ci]+beta).
// Removes the separate finalize_k dispatch.
// ---------------------------------------------------------------------------
__global__ __launch_bounds__(256) void norm_w(const float* __restrict__ attnT,
                                              const double* __restrict__ part,
                                              const float* __restrict__ momp,
                                              unsigned short* __restrict__ o) {
    __shared__ double ls[256], lss[256];
    __shared__ float sAB[2];
    const int tid = threadIdx.x;
    double s = 0.0, ss = 0.0;
    for (int i = tid; i < 288; i += 256) {
        s += part[2 * i]; ss += part[2 * i + 1];
    }
    ls[tid] = s; lss[tid] = ss;
    __syncthreads();
    for (int st = 128; st; st >>= 1) {
        if (tid < st) { ls[tid] += ls[tid + st]; lss[tid] += lss[tid + st]; }
        __syncthreads();
    }
    if (tid == 0) {
        const double n    = (double)(B * FK * C * C);
        const double mean = ls[0] / n;
        double var        = (lss[0] - ls[0] * ls[0] / n) / (n - 1.0);
        if (var < 0.0) var = 0.0;
        const double scale = 1.0 / (sqrt(var) + 1e-4);
        sAB[0] = (float)((double)momp[0] + scale);  // alpha
        sAB[1] = (float)(-mean * scale);            // beta
    }
    __syncthreads();
    const float alpha = sAB[0], beta = sAB[1];

    const int g = (blockIdx.x * 256 + tid) * 4;
    const int chunk = g >> 9, within = g & 511;
    const int lane = within >> 3, t0 = within & 7;
    const int cc = chunk % 6, c2 = chunk / 6;
    const int cot = c2 % 12, pb = c2 / 12;
    const int p = pb % FK, b = pb / FK;
    const int co = cot * 16 + (lane & 15);
    const int ci = cc * 32 + (lane >> 4) * 8 + t0;
    const float4 v = *(const float4*)(attnT + (((size_t)(b * FK + p) * C + co) * C + ci));
    s16x4 r;
    r[0] = (short)f2b(fmaf(alpha, v.x, beta));
    r[1] = (short)f2b(fmaf(alpha, v.y, beta));
    r[2] = (short)f2b(fmaf(alpha, v.z, beta));
    r[3] = (short)f2b(fmaf(alpha, v.w, beta));
    *(s16x4*)(o + g) = r;
}

} // anonymous namespace

extern "C" void kernel_launch(void* const* d_in, const int* in_sizes, int n_in,
                              void* d_out, int out_size, void* d_ws, size_t ws_size,
                              hipStream_t stream) {
    (void)in_sizes; (void)n_in; (void)out_size; (void)ws_size;
    const float* x1   = (const float*)d_in[0];
    const float* x2   = (const float*)d_in[1];
    const float* kw   = (const float*)d_in[2];
    const float* qw   = (const float*)d_in[3];
    const float* momp = (const float*)d_in[4];

    char* ws = (char*)d_ws;
    unsigned short* xpad1 = (unsigned short*)ws;                   // 29,503,488
    unsigned short* xpad2 = (unsigned short*)(ws + 29503488);      // 29,503,488
    unsigned short* kwA   = (unsigned short*)(ws + 59006976);      //    663,552
    unsigned short* qwA   = (unsigned short*)(ws + 59670528);      //    663,552
    unsigned short* kcS   = (unsigned short*)(ws + 60334080);      // 28,311,552
    float*          attnT = (float*)(ws + 88645632);               // 10,616,832
    double*         part  = (double*)(ws + 99262464);              //      4,608
    unsigned short* normW = kcS;            // kcS dead after attn; 5,308,416 B
    unsigned short* qcS   = (unsigned short*)d_out;  // scratch until final conv

    // merged prep: prep_x (4608) + prep_w (2592) + border_zero (582)
    prep_all<<<7782, 256, 0, stream>>>(x1, x2, kw, qw, xpad1, kwA, qwA);

    // both front convs in ONE dispatch (z: bit3 = tensor, low 3 bits = b)
    conv_front<<<dim3(96, 2, 16), 256, 0, stream>>>(
        xpad1, xpad2, kwA, qwA, kcS, qcS);

    attn_mfma<<<dim3(4, 9, 8), 256, 0, stream>>>(kcS, qcS, attnT, part);

    norm_w<<<2592, 256, 0, stream>>>(attnT, part, momp, normW);

    conv_final<<<768, 256, 0, stream>>>(xpad1, normW, (float*)d_out);
}

// Round 14
// 230.336 us; speedup vs baseline: 3.4895x; 1.0429x over previous
//
#include <hip/hip_runtime.h>
#include <math.h>

typedef __attribute__((ext_vector_type(8))) short s16x8;
typedef __attribute__((ext_vector_type(4))) short s16x4;
typedef __attribute__((ext_vector_type(4))) float f32x4;

typedef unsigned int u32;
typedef __attribute__((address_space(3))) u32* lds_u32p;
typedef const __attribute__((address_space(1))) u32* glb_u32p;

namespace {

constexpr int B  = 8;
constexpr int C  = 192;
constexpr int H  = 96;
constexpr int W  = 96;
constexpr int FK = 9;
constexpr int HP = 98;    // padded
constexpr int L  = 1024;  // 32x32 patch grid per phase
constexpr int WCHUNK = FK * 12 * 6;          // 648 packed 1KB chunks per tensor
constexpr int WELEM  = WCHUNK * 512;         // 331776 bf16 elements
constexpr size_t XPAD_ELEMS = (size_t)B * HP * HP * 192;

__device__ inline unsigned short f2b(float f) {
    unsigned int x = __float_as_uint(f);
    x += 0x7fffu + ((x >> 16) & 1u);
    return (unsigned short)(x >> 16);
}

// ---------------------------------------------------------------------------
// MERGED prep: [0,4608) prep_x (x->xpadT bf16 channel-last, both tensors),
// [4608,7200) prep_w (fragment-linear weight pack, both tensors),
// [7200,7782) border_zero (zero pad borders of both xpad tensors).
// ---------------------------------------------------------------------------
__global__ __launch_bounds__(256) void prep_all(const float* __restrict__ x1,
                                                const float* __restrict__ x2,
                                                const float* __restrict__ kw,
                                                const float* __restrict__ qw,
                                                unsigned short* __restrict__ xpadT,
                                                unsigned short* __restrict__ kwA,
                                                unsigned short* __restrict__ qwA) {
    __shared__ float xs[192][33];
    const int gid = blockIdx.x;
    const int tid = threadIdx.x;

    if (gid < 4608) {
        const int bx = gid % 3, by = (gid / 3) % 96, bz = gid / 288;
        const int x0 = bx * 32, y = by;
        const int b = bz & 7, t = bz >> 3;
        const float* x = t ? x2 : x1;
        unsigned short* dst = xpadT + (size_t)t * XPAD_ELEMS;
        for (int e = tid; e < 192 * 32; e += 256) {
            const int ci = e >> 5, xx = e & 31;
            xs[ci][xx] = x[(((size_t)b * C + ci) * H + y) * W + x0 + xx];
        }
        __syncthreads();
        for (int e = tid; e < 32 * 192; e += 256) {
            const int pos = e / 192, ci = e - pos * 192;
            dst[(((size_t)(b * HP + y + 1)) * HP + x0 + pos + 1) * 192 + ci] =
                f2b(xs[ci][pos]);
        }
    } else if (gid < 7200) {
        int idx = (gid - 4608) * 256 + tid;
        const float* src = kw;
        unsigned short* dst = kwA;
        if (idx >= WELEM) { idx -= WELEM; src = qw; dst = qwA; }
        const int chunk = idx >> 9, within = idx & 511;
        const int lane = within >> 3, t = within & 7;
        const int kg = lane >> 4, r15 = lane & 15;
        const int cc = chunk % 6, c2 = chunk / 6;
        const int cot = c2 % 12, p = c2 / 12;
        const int co = cot * 16 + r15;
        const int ci = cc * 32 + kg * 8 + t;
        dst[idx] = f2b(src[((size_t)co * C + ci) * FK + p]);
    } else {
        const int c   = (gid - 7200) * 256 + tid;
        const int c16 = c % 24;
        const int p_  = c / 24;
        const int pos = p_ % 388;
        const int bt  = p_ / 388;      // 0..15 spans xpad1 then xpad2
        int yy, xx;
        if (pos < 98)       { yy = 0;          xx = pos; }
        else if (pos < 196) { yy = 97;         xx = pos - 98; }
        else if (pos < 292) { yy = pos - 195;  xx = 0; }
        else                { yy = pos - 291;  xx = 97; }
        const size_t off = (((size_t)bt * HP + yy) * HP + xx) * 192 + c16 * 8;
        *(s16x8*)(xpadT + off) = (s16x8){0, 0, 0, 0, 0, 0, 0, 0};
    }
}

// ---------------------------------------------------------------------------
// FRONT conv (R8 structure, VGPR 84, no spill) with XCD-affinity block map:
// 1-D grid 3072; xcd = id&7 (linear wg id round-robins XCDs). Each XCD owns
// 2 (tensor,b) pairs; within a pair, y ascends with both sx siblings adjacent
// -> the 2/3-overlapping row windows of y-adjacent blocks hit the SAME L2.
// Inner loop identical to R8/R12 (4 waves 48co x 48s, 2x19.2KB dbuf,
// stage(dy+1) at cc==5, batched 9-af).
// ---------------------------------------------------------------------------
__global__ __launch_bounds__(256, 3)
void conv_front(const unsigned short* __restrict__ xpadA,
                const unsigned short* __restrict__ xpadB,
                const unsigned short* __restrict__ wA,
                const unsigned short* __restrict__ wB,
                void* __restrict__ youtA,
                void* __restrict__ youtB) {
    __shared__ __align__(16) char smem[2][19200];
    const int tid  = threadIdx.x;
    const int id   = blockIdx.x;            // 0..3071
    const int xcd  = id & 7;
    const int j    = id >> 3;               // 0..383
    const int pair = j / 192;               // 0..1
    const int k    = j - pair * 192;
    const int sx   = k & 1;
    const int y    = k >> 1;                // 0..95
    const int bt   = xcd * 2 + pair;        // 0..15
    const int b    = bt & 7;
    const int t    = bt >> 3;
    const unsigned short* xpadT = t ? xpadB : xpadA;
    const unsigned short* wp    = t ? wB : wA;
    void* yout = t ? youtB : youtA;
    const int lane = tid & 63, wc = tid >> 6;
    const int ln15 = lane & 15, kg = lane >> 4;

    // staging: 50 pos x 24 chunks(16B) = 1200 chunks; 4 rounds + 176 tail
    int gfull[4];
#pragma unroll
    for (int it = 0; it < 4; ++it) {
        const int m = it * 256 + tid;
        const int q = m / 24, c16 = m - q * 24;
        gfull[it] = (sx * 48 + q) * 384 + ((c16 * 16) ^ ((q & 7) << 4));
    }
    int gtail = 0;
    if (tid < 176) {
        const int m = 1024 + tid;
        const int q = m / 24, c16 = m - q * 24;
        gtail = (sx * 48 + q) * 384 + ((c16 * 16) ^ ((q & 7) << 4));
    }

    auto stage = [&](char* lb, int prow) {
        const char* rowbase = (const char*)(xpadT + ((size_t)(b * HP + prow)) * HP * 192);
#pragma unroll
        for (int it = 0; it < 4; ++it)
            __builtin_amdgcn_global_load_lds(
                (glb_u32p)(const void*)(rowbase + gfull[it]),
                (lds_u32p)(void*)(lb + it * 4096 + wc * 1024), 16, 0, 0);
        if (tid < 176)
            __builtin_amdgcn_global_load_lds(
                (glb_u32p)(const void*)(rowbase + gtail),
                (lds_u32p)(void*)(lb + 16384 + wc * 1024), 16, 0, 0);
    };

    f32x4 acc[3][3];
#pragma unroll
    for (int i = 0; i < 3; ++i)
#pragma unroll
        for (int j2 = 0; j2 < 3; ++j2)
            acc[i][j2] = (f32x4){0.f, 0.f, 0.f, 0.f};

    stage(smem[0], y);

    for (int dy = 0; dy < 3; ++dy) {
        asm volatile("s_waitcnt vmcnt(0)" ::: "memory");  // stage of this buf done
        __syncthreads();
        const char* lb = smem[dy & 1];

#pragma unroll
        for (int cc = 0; cc < 6; ++cc) {
            s16x8 af[3][3];
#pragma unroll
            for (int dx = 0; dx < 3; ++dx)
#pragma unroll
                for (int i = 0; i < 3; ++i) {
                    const int chunkid = ((3 * dy + dx) * 12 + wc * 3 + i) * 6 + cc;
                    af[dx][i] = *(const s16x8*)(wp + (size_t)chunkid * 512 + lane * 8);
                }
            if (cc == 5) {
                __builtin_amdgcn_sched_barrier(0);   // af issues stay above
                if (dy < 2) stage((char*)smem[(dy + 1) & 1], y + dy + 1);
                __builtin_amdgcn_sched_barrier(0);   // stage issue pinned here
            }
            s16x8 bv[3][3];
#pragma unroll
            for (int j2 = 0; j2 < 3; ++j2)
#pragma unroll
                for (int dx = 0; dx < 3; ++dx) {
                    const int q = j2 * 16 + ln15 + dx;
                    bv[j2][dx] = *(const s16x8*)(lb + q * 384 +
                                    ((cc * 64 + kg * 16) ^ ((q & 7) << 4)));
                }
#pragma unroll
            for (int i = 0; i < 3; ++i)
#pragma unroll
                for (int j2 = 0; j2 < 3; ++j2)
#pragma unroll
                    for (int dx = 0; dx < 3; ++dx)
                        acc[i][j2] = __builtin_amdgcn_mfma_f32_16x16x32_bf16(
                            af[dx][i], bv[j2][dx], acc[i][j2], 0, 0, 0);
        }
    }

    // phase layout: dst[((b*9 + (y%3)*3 + s%3)*192 + co)*1024 + (y/3)*32 + s/3]
    unsigned short* yb = (unsigned short*)yout;
    const int ph = y % 3, lh = y / 3;
    int poff[3];
#pragma unroll
    for (int j2 = 0; j2 < 3; ++j2) {
        const int s  = sx * 48 + j2 * 16 + ln15;
        const int pw = s % 3, lw = s / 3;
        poff[j2] = ((b * FK + ph * 3 + pw) * C) * L + lh * 32 + lw;
    }
#pragma unroll
    for (int i = 0; i < 3; ++i)
#pragma unroll
        for (int rr = 0; rr < 4; ++rr) {
            const int co = wc * 48 + i * 16 + kg * 4 + rr;
#pragma unroll
            for (int j2 = 0; j2 < 3; ++j2)
                yb[(size_t)poff[j2] + co * L] = f2b(acc[i][j2][rr]);
        }
}

// ---------------------------------------------------------------------------
// FINAL conv (R10 wide-s structure, no spill, VGPR 88): wave = 48co x 96s x 1y,
// per-batch normW weights. XCD-batch affinity: b = id&7 -> each XCD runs one
// batch (663KB normW + streamed xpad rows stay in its own L2).
// ---------------------------------------------------------------------------
__global__ __launch_bounds__(256)
void conv_final(const unsigned short* __restrict__ xpadT,
                const unsigned short* __restrict__ wA,
                float* __restrict__ yout) {
    __shared__ __align__(16) char smem[HP * 384];   // 37632 B
    const int tid  = threadIdx.x;
    const int b    = blockIdx.x & 7;    // XCD id on 8-XCD dispatch
    const int y    = blockIdx.x >> 3;
    const int lane = tid & 63, wc = tid >> 6;
    const int ln15 = lane & 15, kg = lane >> 4;

    const unsigned short* wp = wA + (size_t)b * WELEM;

    int gofs[9];
#pragma unroll
    for (int it = 0; it < 9; ++it) {
        const int m = it * 256 + tid;
        const int q = m / 24, c16 = m - q * 24;
        gofs[it] = q * 384 + ((c16 * 16) ^ ((q & 7) << 4));
    }
    int gtail = 0;
    if (tid < 48) {
        const int m = 2304 + tid;
        const int q = m / 24, c16 = m - q * 24;
        gtail = q * 384 + ((c16 * 16) ^ ((q & 7) << 4));
    }

    auto stage = [&](int prow) {
        const char* rb = (const char*)(xpadT + ((size_t)(b * HP + prow)) * HP * 192);
#pragma unroll
        for (int it = 0; it < 9; ++it)
            __builtin_amdgcn_global_load_lds(
                (glb_u32p)(const void*)(rb + gofs[it]),
                (lds_u32p)(void*)(smem + it * 4096 + wc * 1024), 16, 0, 0);
        if (tid < 48)
            __builtin_amdgcn_global_load_lds(
                (glb_u32p)(const void*)(rb + gtail),
                (lds_u32p)(void*)(smem + 36864 + wc * 1024), 16, 0, 0);
    };

    f32x4 acc[3][6];
#pragma unroll
    for (int i = 0; i < 3; ++i)
#pragma unroll
        for (int j = 0; j < 6; ++j)
            acc[i][j] = (f32x4){0.f, 0.f, 0.f, 0.f};

    stage(y);

#pragma unroll 1
    for (int dy = 0; dy < 3; ++dy) {
        asm volatile("s_waitcnt vmcnt(0)" ::: "memory");
        __syncthreads();

#pragma unroll 1
        for (int cc = 0; cc < 6; ++cc) {
#pragma unroll
            for (int dx = 0; dx < 3; ++dx) {
                const int cid = (((3 * dy + dx) * 12 + wc * 3) * 6 + cc);
                const s16x8 af0 = *(const s16x8*)(wp + (size_t)cid * 512 + lane * 8);
                const s16x8 af1 = *(const s16x8*)(wp + (size_t)(cid + 6) * 512 + lane * 8);
                const s16x8 af2 = *(const s16x8*)(wp + (size_t)(cid + 12) * 512 + lane * 8);
#pragma unroll
                for (int j = 0; j < 6; ++j) {
                    const int q = j * 16 + ln15 + dx;
                    const s16x8 bv = *(const s16x8*)(smem + q * 384 +
                                        ((cc * 64 + kg * 16) ^ ((q & 7) << 4)));
                    acc[0][j] = __builtin_amdgcn_mfma_f32_16x16x32_bf16(af0, bv, acc[0][j], 0, 0, 0);
                    acc[1][j] = __builtin_amdgcn_mfma_f32_16x16x32_bf16(af1, bv, acc[1][j], 0, 0, 0);
                    acc[2][j] = __builtin_amdgcn_mfma_f32_16x16x32_bf16(af2, bv, acc[2][j], 0, 0, 0);
                }
            }
        }
        if (dy < 2) {
            __syncthreads();          // all waves done reading smem
            stage(y + dy + 1);
        }
    }

#pragma unroll
    for (int i = 0; i < 3; ++i)
#pragma unroll
        for (int rr = 0; rr < 4; ++rr) {
            const int co = wc * 48 + i * 16 + kg * 4 + rr;
            const size_t base = (((size_t)b * C + co) * H + y) * W;
#pragma unroll
            for (int j = 0; j < 6; ++j)
                yout[base + j * 16 + ln15] = acc[i][j][rr];
        }
}

// ---------------------------------------------------------------------------
// attn MFMA with XCD-batch affinity: 1-D grid 288; xcd = id&7 = b -> each XCD
// owns one batch; the 4 (of,cf) quarters of each (b,p) are temporally
// adjacent so the 393KB conv-output slices are read once from L3, rest L2.
// Block = 96c x 96o quarter, 4 waves 48x48, BK=64 double-buffered staging.
// Epilogue: attnT[b][p][o][c] f32 + fused f64 sum/ssq partials.
// ---------------------------------------------------------------------------
__global__ __launch_bounds__(256, 3)
void attn_mfma(const unsigned short* __restrict__ kcS,
               const unsigned short* __restrict__ qcS,
               float* __restrict__ attnT,
               double* __restrict__ part) {
    __shared__ __align__(16) char smem[2][24576];   // [buf][A 12KB | B 12KB]
    const int tid  = threadIdx.x;
    const int lane = tid & 63, wid = tid >> 6;
    const int wq   = wid & 1, wp = wid >> 1;
    const int ln15 = lane & 15, kg = lane >> 4;
    const int id   = blockIdx.x;        // 0..287
    const int b    = id & 7;            // XCD id
    const int j5   = id >> 3;           // 0..35
    const int quarter = j5 & 3;
    const int p    = j5 >> 2;           // 0..8
    const int of   = quarter & 1, cf = quarter >> 1;

    const char* Abase = (const char*)(kcS + ((size_t)(b * FK + p) * C + cf * 96) * L);
    const char* Bbase = (const char*)(qcS + ((size_t)(b * FK + p) * C + of * 96) * L);

    int gofs[3];
#pragma unroll
    for (int it = 0; it < 3; ++it) {
        const int chunk = it * 256 + tid;
        const int row = chunk >> 3, c16 = chunk & 7;
        gofs[it] = row * 2048 + ((c16 * 16) ^ ((row & 7) << 4));
    }

    auto stage = [&](int bufi, int t) {
        const char* Ab = Abase + t * 128;
        const char* Bb = Bbase + t * 128;
        char* lb = (char*)smem[bufi];
#pragma unroll
        for (int it = 0; it < 3; ++it)
            __builtin_amdgcn_global_load_lds(
                (glb_u32p)(const void*)(Ab + gofs[it]),
                (lds_u32p)(void*)(lb + it * 4096 + wid * 1024), 16, 0, 0);
#pragma unroll
        for (int it = 0; it < 3; ++it)
            __builtin_amdgcn_global_load_lds(
                (glb_u32p)(const void*)(Bb + gofs[it]),
                (lds_u32p)(void*)(lb + 12288 + it * 4096 + wid * 1024), 16, 0, 0);
    };

    f32x4 acc[3][3];
#pragma unroll
    for (int i = 0; i < 3; ++i)
#pragma unroll
        for (int j = 0; j < 3; ++j)
            acc[i][j] = (f32x4){0.f, 0.f, 0.f, 0.f};

    stage(0, 0);
    asm volatile("s_waitcnt vmcnt(0)" ::: "memory");
    __syncthreads();

    for (int t = 0; t < 16; ++t) {
        if (t < 15) stage((t + 1) & 1, t + 1);
        const char* lb = (const char*)smem[t & 1];
#pragma unroll
        for (int ks = 0; ks < 2; ++ks) {
            s16x8 af[3], bf[3];
#pragma unroll
            for (int i = 0; i < 3; ++i) {
                const int row = wp * 48 + i * 16 + ln15;
                af[i] = *(const s16x8*)(lb + row * 128 +
                                        ((ks * 64 + kg * 16) ^ ((row & 7) << 4)));
            }
#pragma unroll
            for (int j = 0; j < 3; ++j) {
                const int row = wq * 48 + j * 16 + ln15;
                bf[j] = *(const s16x8*)(lb + 12288 + row * 128 +
                                        ((ks * 64 + kg * 16) ^ ((row & 7) << 4)));
            }
#pragma unroll
            for (int i = 0; i < 3; ++i)
#pragma unroll
                for (int j = 0; j < 3; ++j)
                    acc[i][j] = __builtin_amdgcn_mfma_f32_16x16x32_bf16(
                        af[i], bf[j], acc[i][j], 0, 0, 0);
        }
        if (t < 15) {
            asm volatile("s_waitcnt vmcnt(0)" ::: "memory");
            __syncthreads();
        }
    }

    __syncthreads();
    double s = 0.0, ss = 0.0;
#pragma unroll
    for (int i = 0; i < 3; ++i)
#pragma unroll
        for (int j = 0; j < 3; ++j)
#pragma unroll
            for (int r = 0; r < 4; ++r) {
                const double v = (double)acc[i][j][r];
                s += v; ss += v * v;
            }
    double* ls  = (double*)&smem[0][0];
    double* lss = ls + 256;
    ls[tid] = s; lss[tid] = ss;
    __syncthreads();
    for (int st = 128; st; st >>= 1) {
        if (tid < st) { ls[tid] += ls[tid + st]; lss[tid] += lss[tid + st]; }
        __syncthreads();
    }
    if (tid == 0) {
        const int bf_ = ((b * FK + p) << 2) + quarter;
        part[2 * bf_]     = ls[0];
        part[2 * bf_ + 1] = lss[0];
    }

    float* ap = attnT + (size_t)(b * FK + p) * C * C;
#pragma unroll
    for (int i = 0; i < 3; ++i) {
        const int c0 = cf * 96 + wp * 48 + i * 16 + kg * 4;
#pragma unroll
        for (int j = 0; j < 3; ++j) {
            const int o = of * 96 + wq * 48 + j * 16 + ln15;
            *(f32x4*)(ap + o * C + c0) = acc[i][j];
        }
    }
}

// ---------------------------------------------------------------------------
// normW packed + INLINE finalize: every block redundantly reduces the 288
// f64 partial pairs (4.6KB, L2-hot, deterministic) -> alpha/beta, then
// out[b][chunk][lane][t] = bf16(alpha*attnT[b][p][co][ci]+beta).
// ---------------------------------------------------------------------------
__global__ __launch_bounds__(256) void norm_w(const float* __restrict__ attnT,
                                              const double* __restrict__ part,
                                              const float* __restrict__ momp,
                                              unsigned short* __restrict__ o) {
    __shared__ double ls[256], lss[256];
    __shared__ float sAB[2];
    const int tid = threadIdx.x;
    double s = 0.0, ss = 0.0;
    for (int i = tid; i < 288; i += 256) {
        s += part[2 * i]; ss += part[2 * i + 1];
    }
    ls[tid] = s; lss[tid] = ss;
    __syncthreads();
    for (int st = 128; st; st >>= 1) {
        if (tid < st) { ls[tid] += ls[tid + st]; lss[tid] += lss[tid + st]; }
        __syncthreads();
    }
    if (tid == 0) {
        const double n    = (double)(B * FK * C * C);
        const double mean = ls[0] / n;
        double var        = (lss[0] - ls[0] * ls[0] / n) / (n - 1.0);
        if (var < 0.0) var = 0.0;
        const double scale = 1.0 / (sqrt(var) + 1e-4);
        sAB[0] = (float)((double)momp[0] + scale);  // alpha
        sAB[1] = (float)(-mean * scale);            // beta
    }
    __syncthreads();
    const float alpha = sAB[0], beta = sAB[1];

    const int g = (blockIdx.x * 256 + tid) * 4;
    const int chunk = g >> 9, within = g & 511;
    const int lane = within >> 3, t0 = within & 7;
    const int cc = chunk % 6, c2 = chunk / 6;
    const int cot = c2 % 12, pb = c2 / 12;
    const int p = pb % FK, b = pb / FK;
    const int co = cot * 16 + (lane & 15);
    const int ci = cc * 32 + (lane >> 4) * 8 + t0;
    const float4 v = *(const float4*)(attnT + (((size_t)(b * FK + p) * C + co) * C + ci));
    s16x4 r;
    r[0] = (short)f2b(fmaf(alpha, v.x, beta));
    r[1] = (short)f2b(fmaf(alpha, v.y, beta));
    r[2] = (short)f2b(fmaf(alpha, v.z, beta));
    r[3] = (short)f2b(fmaf(alpha, v.w, beta));
    *(s16x4*)(o + g) = r;
}

} // anonymous namespace

extern "C" void kernel_launch(void* const* d_in, const int* in_sizes, int n_in,
                              void* d_out, int out_size, void* d_ws, size_t ws_size,
                              hipStream_t stream) {
    (void)in_sizes; (void)n_in; (void)out_size; (void)ws_size;
    const float* x1   = (const float*)d_in[0];
    const float* x2   = (const float*)d_in[1];
    const float* kw   = (const float*)d_in[2];
    const float* qw   = (const float*)d_in[3];
    const float* momp = (const float*)d_in[4];

    char* ws = (char*)d_ws;
    unsigned short* xpad1 = (unsigned short*)ws;                   // 29,503,488
    unsigned short* xpad2 = (unsigned short*)(ws + 29503488);      // 29,503,488
    unsigned short* kwA   = (unsigned short*)(ws + 59006976);      //    663,552
    unsigned short* qwA   = (unsigned short*)(ws + 59670528);      //    663,552
    unsigned short* kcS   = (unsigned short*)(ws + 60334080);      // 28,311,552
    float*          attnT = (float*)(ws + 88645632);               // 10,616,832
    double*         part  = (double*)(ws + 99262464);              //      4,608
    unsigned short* normW = kcS;            // kcS dead after attn; 5,308,416 B
    unsigned short* qcS   = (unsigned short*)d_out;  // scratch until final conv

    // merged prep: prep_x (4608) + prep_w (2592) + border_zero (582)
    prep_all<<<7782, 256, 0, stream>>>(x1, x2, kw, qw, xpad1, kwA, qwA);

    // both front convs in ONE dispatch, XCD-affinity mapped
    conv_front<<<3072, 256, 0, stream>>>(xpad1, xpad2, kwA, qwA, kcS, qcS);

    attn_mfma<<<288, 256, 0, stream>>>(kcS, qcS, attnT, part);

    norm_w<<<2592, 256, 0, stream>>>(attnT, part, momp, normW);

    conv_final<<<768, 256, 0, stream>>>(xpad1, normW, (float*)d_out);
}